// Round 1
// baseline (273.634 us; speedup 1.0000x reference)
//
#include <hip/hip_runtime.h>
#include <hip/hip_bf16.h>
#include <math.h>

#define NROWS 8192
#define DDIM  768
#define TEMP_INV 14.285714285714286f   // 1/0.07
#define EPSX 1e-6f

typedef __attribute__((ext_vector_type(8))) short bf16x8;
typedef __attribute__((ext_vector_type(4))) float f32x4;
typedef unsigned short u16;
typedef unsigned int   u32;

// round-to-nearest-even fp32 -> bf16 bits
__device__ __forceinline__ u16 f2bf(float x){
  u32 u = __float_as_uint(x);
  u = (u + 0x7fffu + ((u >> 16) & 1u)) >> 16;
  return (u16)u;
}

// ---------------- prep: bf16 convert + row norms + diagonal dot ----------------
__global__ __launch_bounds__(256) void prep_kernel(
    const float* __restrict__ v, const float* __restrict__ t, const float* __restrict__ cptr,
    u16* __restrict__ vb, u16* __restrict__ tb,
    float* __restrict__ vtime, float* __restrict__ ttime, float* __restrict__ diag)
{
  int row = blockIdx.x;
  int tid = threadIdx.x;
  float inv_c = 1.0f / cptr[0];
  const float* vr = v + (size_t)row * DDIM;
  const float* tr = t + (size_t)row * DDIM;
  u16* vbr = vb + (size_t)row * DDIM;
  u16* tbr = tb + (size_t)row * DDIM;
  float sv = 0.f, st = 0.f, dd = 0.f;
  for (int k = tid; k < DDIM; k += 256){
    float a = vr[k], b = tr[k];
    sv += a*a; st += b*b; dd += a*b;
    vbr[k] = f2bf(a);
    tbr[k] = f2bf(b);
  }
  for (int o = 32; o; o >>= 1){
    sv += __shfl_down(sv, o);
    st += __shfl_down(st, o);
    dd += __shfl_down(dd, o);
  }
  __shared__ float red[3][4];
  int lane = tid & 63, wid = tid >> 6;
  if (!lane){ red[0][wid]=sv; red[1][wid]=st; red[2][wid]=dd; }
  __syncthreads();
  if (!tid){
    float SV = red[0][0]+red[0][1]+red[0][2]+red[0][3];
    float ST = red[1][0]+red[1][1]+red[1][2]+red[1][3];
    float DD = red[2][0]+red[2][1]+red[2][2]+red[2][3];
    vtime[row] = sqrtf(inv_c + SV);
    ttime[row] = sqrtf(inv_c + ST);
    diag[row]  = DD;
  }
}

// ---------------- main: 128x128 MFMA tile + fused logit/online-LSE epilogue ----------------
__global__ __launch_bounds__(256) void tile_kernel(
    const u16* __restrict__ vb, const u16* __restrict__ tb,
    const float* __restrict__ vtime, const float* __restrict__ ttime,
    const float* __restrict__ cptr,
    float* __restrict__ rowPmax, float* __restrict__ rowPsum,
    float* __restrict__ colPmax, float* __restrict__ colPsum)
{
  const int bx = blockIdx.x;   // column block (t side)
  const int by = blockIdx.y;   // row block (v side)
  const int tid = threadIdx.x;
  const int lane = tid & 63, wid = tid >> 6;
  const int wm = wid >> 1, wn = wid & 1;      // 2x2 wave grid, each wave 64x64
  const int lo = lane & 15, hi = lane >> 4;

  __shared__ u16 As[128*32];
  __shared__ u16 Bs[128*32];
  __shared__ float vtl[128], ttl[128];
  __shared__ float redm[2][128], reds[2][128];

  if (tid < 128){
    vtl[tid] = vtime[by*128 + tid];
    ttl[tid] = ttime[bx*128 + tid];
  }

  const float c = cptr[0];
  const float slog = -(1.0f/sqrtf(c)) * TEMP_INV;

  f32x4 acc[4][4];
  #pragma unroll
  for (int m = 0; m < 4; m++)
    #pragma unroll
    for (int n = 0; n < 4; n++)
      acc[m][n] = (f32x4){0.f,0.f,0.f,0.f};

  const u16* Abase = vb + (size_t)(by*128) * DDIM;
  const u16* Bbase = tb + (size_t)(bx*128) * DDIM;

  for (int kk = 0; kk < DDIM; kk += 32){
    __syncthreads();
    {
      int idx0 = tid, idx1 = 256 + tid;
      const uint4 a0 = *(const uint4*)(Abase + (size_t)(idx0>>2)*DDIM + kk + (idx0&3)*8);
      const uint4 a1 = *(const uint4*)(Abase + (size_t)(idx1>>2)*DDIM + kk + (idx1&3)*8);
      const uint4 b0 = *(const uint4*)(Bbase + (size_t)(idx0>>2)*DDIM + kk + (idx0&3)*8);
      const uint4 b1 = *(const uint4*)(Bbase + (size_t)(idx1>>2)*DDIM + kk + (idx1&3)*8);
      ((uint4*)As)[idx0] = a0; ((uint4*)As)[idx1] = a1;
      ((uint4*)Bs)[idx0] = b0; ((uint4*)Bs)[idx1] = b1;
    }
    __syncthreads();
    bf16x8 af[4], bfr[4];
    #pragma unroll
    for (int m = 0; m < 4; m++)
      af[m] = *(const bf16x8*)(As + (wm*64 + m*16 + lo)*32 + hi*8);
    #pragma unroll
    for (int n = 0; n < 4; n++)
      bfr[n] = *(const bf16x8*)(Bs + (wn*64 + n*16 + lo)*32 + hi*8);
    #pragma unroll
    for (int m = 0; m < 4; m++)
      #pragma unroll
      for (int n = 0; n < 4; n++)
        acc[m][n] = __builtin_amdgcn_mfma_f32_16x16x32_bf16(af[m], bfr[n], acc[m][n], 0, 0, 0);
  }

  // ---- epilogue: dot -> logit (overwrite acc) ----
  // C/D layout: col = lane&15, row = (lane>>4)*4 + j   [m89]
  #pragma unroll
  for (int m = 0; m < 4; m++){
    #pragma unroll
    for (int n = 0; n < 4; n++){
      #pragma unroll
      for (int j = 0; j < 4; j++){
        int r  = wm*64 + m*16 + hi*4 + j;
        int cc = wn*64 + n*16 + lo;
        float arg = c * (vtl[r] * ttl[cc] - acc[m][n][j]);
        arg = fmaxf(arg, 1.0f + EPSX);
        acc[m][n][j] = slog * __logf(arg + sqrtf(arg*arg - 1.0f));
      }
    }
  }

  // ---- per-row (max, sumexp) over this tile's 128 cols ----
  #pragma unroll
  for (int m = 0; m < 4; m++){
    #pragma unroll
    for (int j = 0; j < 4; j++){
      float mx = fmaxf(fmaxf(acc[m][0][j], acc[m][1][j]), fmaxf(acc[m][2][j], acc[m][3][j]));
      #pragma unroll
      for (int msk = 1; msk < 16; msk <<= 1) mx = fmaxf(mx, __shfl_xor(mx, msk));
      float s = 0.f;
      #pragma unroll
      for (int n = 0; n < 4; n++) s += __expf(acc[m][n][j] - mx);
      #pragma unroll
      for (int msk = 1; msk < 16; msk <<= 1) s += __shfl_xor(s, msk);
      if (lo == 0){
        redm[wn][wm*64 + m*16 + hi*4 + j] = mx;
        reds[wn][wm*64 + m*16 + hi*4 + j] = s;
      }
    }
  }
  __syncthreads();
  if (tid < 128){
    float m0 = redm[0][tid], m1 = redm[1][tid];
    float M = fmaxf(m0, m1);
    float S = reds[0][tid]*__expf(m0 - M) + reds[1][tid]*__expf(m1 - M);
    rowPmax[(size_t)bx*NROWS + by*128 + tid] = M;
    rowPsum[(size_t)bx*NROWS + by*128 + tid] = S;
  }
  __syncthreads();

  // ---- per-col (max, sumexp) over this tile's 128 rows ----
  #pragma unroll
  for (int n = 0; n < 4; n++){
    float mx = -__builtin_inff();
    #pragma unroll
    for (int m = 0; m < 4; m++)
      #pragma unroll
      for (int j = 0; j < 4; j++) mx = fmaxf(mx, acc[m][n][j]);
    mx = fmaxf(mx, __shfl_xor(mx, 16));
    mx = fmaxf(mx, __shfl_xor(mx, 32));
    float s = 0.f;
    #pragma unroll
    for (int m = 0; m < 4; m++)
      #pragma unroll
      for (int j = 0; j < 4; j++) s += __expf(acc[m][n][j] - mx);
    s += __shfl_xor(s, 16);
    s += __shfl_xor(s, 32);
    if (hi == 0){
      redm[wm][wn*64 + n*16 + lo] = mx;
      reds[wm][wn*64 + n*16 + lo] = s;
    }
  }
  __syncthreads();
  if (tid < 128){
    float m0 = redm[0][tid], m1 = redm[1][tid];
    float M = fmaxf(m0, m1);
    float S = reds[0][tid]*__expf(m0 - M) + reds[1][tid]*__expf(m1 - M);
    colPmax[(size_t)by*NROWS + bx*128 + tid] = M;
    colPsum[(size_t)by*NROWS + bx*128 + tid] = S;
  }
}

// ---------------- stage 2: merge 64 partials per row/col, sum LSE per block ----------------
__global__ __launch_bounds__(256) void lse_reduce(
    const float* __restrict__ rowPmax, const float* __restrict__ rowPsum,
    const float* __restrict__ colPmax, const float* __restrict__ colPsum,
    float* __restrict__ psums)
{
  const int i = blockIdx.x * 256 + threadIdx.x;
  const float* Pm = blockIdx.y ? colPmax : rowPmax;
  const float* Ps = blockIdx.y ? colPsum : rowPsum;
  float M = -__builtin_inff();
  float S = 0.f;
  for (int b = 0; b < 64; b++){
    float m = Pm[(size_t)b*NROWS + i];
    float s = Ps[(size_t)b*NROWS + i];
    float Mn = fmaxf(M, m);
    S = S * __expf(M - Mn) + s * __expf(m - Mn);
    M = Mn;
  }
  float lse = M + __logf(S);
  for (int o = 32; o; o >>= 1) lse += __shfl_down(lse, o);
  __shared__ float red[4];
  int lane = threadIdx.x & 63, wid = threadIdx.x >> 6;
  if (!lane) red[wid] = lse;
  __syncthreads();
  if (!threadIdx.x)
    psums[blockIdx.y*32 + blockIdx.x] = red[0]+red[1]+red[2]+red[3];
}

// ---------------- final: diagonal logits + combine ----------------
__global__ __launch_bounds__(256) void final_kernel(
    const float* __restrict__ psums, const float* __restrict__ vtime,
    const float* __restrict__ ttime, const float* __restrict__ diag,
    const float* __restrict__ cptr, float* __restrict__ out)
{
  int tid = threadIdx.x;
  float c = cptr[0];
  float slog = -(1.0f/sqrtf(c)) * TEMP_INV;
  float dsum = 0.f;
  for (int i = tid; i < NROWS; i += 256){
    float arg = c * (vtime[i]*ttime[i] - diag[i]);
    arg = fmaxf(arg, 1.0f + EPSX);
    dsum += slog * __logf(arg + sqrtf(arg*arg - 1.0f));
  }
  for (int o = 32; o; o >>= 1) dsum += __shfl_down(dsum, o);
  __shared__ float red[4];
  if (!(tid & 63)) red[tid >> 6] = dsum;
  __syncthreads();
  if (!tid){
    float dtot = red[0]+red[1]+red[2]+red[3];
    float rs = 0.f, cs = 0.f;
    for (int k = 0; k < 32; k++){ rs += psums[k]; cs += psums[32+k]; }
    out[0] = 0.5f*(rs + cs)/NROWS - dtot/NROWS;
  }
}

extern "C" void kernel_launch(void* const* d_in, const int* in_sizes, int n_in,
                              void* d_out, int out_size, void* d_ws, size_t ws_size,
                              hipStream_t stream) {
  const float* v = (const float*)d_in[0];
  const float* t = (const float*)d_in[1];
  const float* c = (const float*)d_in[2];

  char* ws = (char*)d_ws;
  const size_t NB = (size_t)NROWS * DDIM * sizeof(u16);   // 12,582,912
  u16*   vb      = (u16*)(ws);
  u16*   tb      = (u16*)(ws + NB);
  float* vtime   = (float*)(ws + 2*NB);
  float* ttime   = (float*)(ws + 2*NB + NROWS*4);
  float* diag    = (float*)(ws + 2*NB + 2*(size_t)NROWS*4);
  char*  p       = ws + 2*NB + 3*(size_t)NROWS*4;
  const size_t PB = (size_t)64 * NROWS * 4;               // 2 MB each
  float* rowPmax = (float*)(p);
  float* rowPsum = (float*)(p + PB);
  float* colPmax = (float*)(p + 2*PB);
  float* colPsum = (float*)(p + 3*PB);
  float* psums   = (float*)(p + 4*PB);

  prep_kernel<<<NROWS, 256, 0, stream>>>(v, t, c, vb, tb, vtime, ttime, diag);
  tile_kernel<<<dim3(64, 64), 256, 0, stream>>>(vb, tb, vtime, ttime, c,
                                                rowPmax, rowPsum, colPmax, colPsum);
  lse_reduce<<<dim3(32, 2), 256, 0, stream>>>(rowPmax, rowPsum, colPmax, colPsum, psums);
  final_kernel<<<1, 256, 0, stream>>>(psums, vtime, ttime, diag, c, (float*)d_out);
}

// Round 2
// 258.975 us; speedup vs baseline: 1.0566x; 1.0566x over previous
//
#include <hip/hip_runtime.h>
#include <hip/hip_bf16.h>
#include <math.h>

#define NROWS 8192
#define DDIM  768
#define TEMP_INV 14.285714285714286f   // 1/0.07
#define EPSX 1e-6f

typedef __attribute__((ext_vector_type(8))) short bf16x8;
typedef __attribute__((ext_vector_type(4))) float f32x4;
typedef unsigned short u16;
typedef unsigned int   u32;

#define GLOAD16(gaddr, laddr)                                                   \
  __builtin_amdgcn_global_load_lds(                                             \
      (const __attribute__((address_space(1))) u32*)(gaddr),                    \
      (__attribute__((address_space(3))) u32*)(laddr), 16, 0, 0)

// round-to-nearest-even fp32 -> bf16 bits
__device__ __forceinline__ u16 f2bf(float x){
  u32 u = __float_as_uint(x);
  u = (u + 0x7fffu + ((u >> 16) & 1u)) >> 16;
  return (u16)u;
}

// ---------------- prep: bf16 convert + row norms + diagonal dot ----------------
__global__ __launch_bounds__(256) void prep_kernel(
    const float* __restrict__ v, const float* __restrict__ t, const float* __restrict__ cptr,
    u16* __restrict__ vb, u16* __restrict__ tb,
    float* __restrict__ vtime, float* __restrict__ ttime, float* __restrict__ diag)
{
  int row = blockIdx.x;
  int tid = threadIdx.x;
  float inv_c = 1.0f / cptr[0];
  const float* vr = v + (size_t)row * DDIM;
  const float* tr = t + (size_t)row * DDIM;
  u16* vbr = vb + (size_t)row * DDIM;
  u16* tbr = tb + (size_t)row * DDIM;
  float sv = 0.f, st = 0.f, dd = 0.f;
  for (int k = tid; k < DDIM; k += 256){
    float a = vr[k], b = tr[k];
    sv += a*a; st += b*b; dd += a*b;
    vbr[k] = f2bf(a);
    tbr[k] = f2bf(b);
  }
  for (int o = 32; o; o >>= 1){
    sv += __shfl_down(sv, o);
    st += __shfl_down(st, o);
    dd += __shfl_down(dd, o);
  }
  __shared__ float red[3][4];
  int lane = tid & 63, wid = tid >> 6;
  if (!lane){ red[0][wid]=sv; red[1][wid]=st; red[2][wid]=dd; }
  __syncthreads();
  if (!tid){
    float SV = red[0][0]+red[0][1]+red[0][2]+red[0][3];
    float ST = red[1][0]+red[1][1]+red[1][2]+red[1][3];
    float DD = red[2][0]+red[2][1]+red[2][2]+red[2][3];
    vtime[row] = sqrtf(inv_c + SV);
    ttime[row] = sqrtf(inv_c + ST);
    diag[row]  = DD;
  }
}

// ---------------- main: 128x128 MFMA tile, global_load_lds staging + swizzle ----------------
// LDS tile layout: row-major [128][32] bf16 (row stride 64B). Slot (row, chunk)
// [chunk = 16B unit] holds GLOBAL chunk (chunk ^ ((row>>1)&3)) of that row's
// 32-col K-slice. global_load_lds writes linearly (lane*16B); the source
// address carries the swizzle; ds_read applies the same XOR (involution).
__global__ __launch_bounds__(256) void tile_kernel(
    const u16* __restrict__ vb, const u16* __restrict__ tb,
    const float* __restrict__ vtime, const float* __restrict__ ttime,
    const float* __restrict__ cptr,
    float* __restrict__ rowPmax, float* __restrict__ rowPsum,
    float* __restrict__ colPmax, float* __restrict__ colPsum)
{
  const int bx = blockIdx.x;   // column block (t side)
  const int by = blockIdx.y;   // row block (v side)
  const int tid = threadIdx.x;
  const int lane = tid & 63, wid = tid >> 6;
  const int wm = wid >> 1, wn = wid & 1;      // 2x2 wave grid, each wave 64x64
  const int lo = lane & 15, hi = lane >> 4;

  __shared__ u16 As[128*32];
  __shared__ u16 Bs[128*32];
  __shared__ float vtl[128], ttl[128];
  __shared__ float redm[2][128], reds[2][128];

  if (tid < 128){
    vtl[tid] = vtime[by*128 + tid];
    ttl[tid] = ttime[bx*128 + tid];
  }

  const float c = cptr[0];
  const float slog = -(1.0f/sqrtf(c)) * TEMP_INV;

  f32x4 acc[4][4];
  #pragma unroll
  for (int m = 0; m < 4; m++)
    #pragma unroll
    for (int n = 0; n < 4; n++)
      acc[m][n] = (f32x4){0.f,0.f,0.f,0.f};

  const u16* Abase = vb + (size_t)(by*128) * DDIM;
  const u16* Bbase = tb + (size_t)(bx*128) * DDIM;

  // --- staging addresses (per-thread global src with inverse swizzle) ---
  const int r0 = tid >> 2, cc0 = tid & 3;
  const int r1 = r0 + 64;
  const int gs0 = cc0 ^ ((r0 >> 1) & 3);
  const int gs1 = cc0 ^ ((r1 >> 1) & 3);
  const u16* gA0 = Abase + (size_t)r0*DDIM + gs0*8;
  const u16* gA1 = Abase + (size_t)r1*DDIM + gs1*8;
  const u16* gB0 = Bbase + (size_t)r0*DDIM + gs0*8;
  const u16* gB1 = Bbase + (size_t)r1*DDIM + gs1*8;
  // wave-uniform LDS dest bases (u16 units): rows [16w,16w+16) = 512 u16 per wave
  u16* lA0 = As + wid*512;
  u16* lA1 = As + 2048 + wid*512;
  u16* lB0 = Bs + wid*512;
  u16* lB1 = Bs + 2048 + wid*512;

  // --- fragment read offsets (u16 units), swizzled, constant across K-steps ---
  int aoff[4], boff[4];
  #pragma unroll
  for (int m = 0; m < 4; m++){
    int r = wm*64 + m*16 + lo;
    aoff[m] = r*32 + ((hi ^ ((r >> 1) & 3)) * 8);
  }
  #pragma unroll
  for (int n = 0; n < 4; n++){
    int r = wn*64 + n*16 + lo;
    boff[n] = r*32 + ((hi ^ ((r >> 1) & 3)) * 8);
  }

  for (int kk = 0; kk < DDIM; kk += 32){
    __syncthreads();
    GLOAD16(gA0 + kk, lA0);
    GLOAD16(gA1 + kk, lA1);
    GLOAD16(gB0 + kk, lB0);
    GLOAD16(gB1 + kk, lB1);
    __syncthreads();
    bf16x8 af[4], bfr[4];
    #pragma unroll
    for (int m = 0; m < 4; m++) af[m]  = *(const bf16x8*)(As + aoff[m]);
    #pragma unroll
    for (int n = 0; n < 4; n++) bfr[n] = *(const bf16x8*)(Bs + boff[n]);
    #pragma unroll
    for (int m = 0; m < 4; m++)
      #pragma unroll
      for (int n = 0; n < 4; n++)
        acc[m][n] = __builtin_amdgcn_mfma_f32_16x16x32_bf16(af[m], bfr[n], acc[m][n], 0, 0, 0);
  }

  // ---- epilogue: dot -> logit (overwrite acc) ----
  // C/D layout: col = lane&15, row = (lane>>4)*4 + j   [m89]
  #pragma unroll
  for (int m = 0; m < 4; m++){
    #pragma unroll
    for (int n = 0; n < 4; n++){
      #pragma unroll
      for (int j = 0; j < 4; j++){
        int r  = wm*64 + m*16 + hi*4 + j;
        int cc = wn*64 + n*16 + lo;
        float arg = c * (vtl[r] * ttl[cc] - acc[m][n][j]);
        arg = fmaxf(arg, 1.0f + EPSX);
        acc[m][n][j] = slog * __logf(arg + sqrtf(arg*arg - 1.0f));
      }
    }
  }

  // ---- per-row (max, sumexp) over this tile's 128 cols ----
  #pragma unroll
  for (int m = 0; m < 4; m++){
    #pragma unroll
    for (int j = 0; j < 4; j++){
      float mx = fmaxf(fmaxf(acc[m][0][j], acc[m][1][j]), fmaxf(acc[m][2][j], acc[m][3][j]));
      #pragma unroll
      for (int msk = 1; msk < 16; msk <<= 1) mx = fmaxf(mx, __shfl_xor(mx, msk));
      float s = 0.f;
      #pragma unroll
      for (int n = 0; n < 4; n++) s += __expf(acc[m][n][j] - mx);
      #pragma unroll
      for (int msk = 1; msk < 16; msk <<= 1) s += __shfl_xor(s, msk);
      if (lo == 0){
        redm[wn][wm*64 + m*16 + hi*4 + j] = mx;
        reds[wn][wm*64 + m*16 + hi*4 + j] = s;
      }
    }
  }
  __syncthreads();
  if (tid < 128){
    float m0 = redm[0][tid], m1 = redm[1][tid];
    float M = fmaxf(m0, m1);
    float S = reds[0][tid]*__expf(m0 - M) + reds[1][tid]*__expf(m1 - M);
    rowPmax[(size_t)bx*NROWS + by*128 + tid] = M;
    rowPsum[(size_t)bx*NROWS + by*128 + tid] = S;
  }
  __syncthreads();

  // ---- per-col (max, sumexp) over this tile's 128 rows ----
  #pragma unroll
  for (int n = 0; n < 4; n++){
    float mx = -__builtin_inff();
    #pragma unroll
    for (int m = 0; m < 4; m++)
      #pragma unroll
      for (int j = 0; j < 4; j++) mx = fmaxf(mx, acc[m][n][j]);
    mx = fmaxf(mx, __shfl_xor(mx, 16));
    mx = fmaxf(mx, __shfl_xor(mx, 32));
    float s = 0.f;
    #pragma unroll
    for (int m = 0; m < 4; m++)
      #pragma unroll
      for (int j = 0; j < 4; j++) s += __expf(acc[m][n][j] - mx);
    s += __shfl_xor(s, 16);
    s += __shfl_xor(s, 32);
    if (hi == 0){
      redm[wm][wn*64 + n*16 + lo] = mx;
      reds[wm][wn*64 + n*16 + lo] = s;
    }
  }
  __syncthreads();
  if (tid < 128){
    float m0 = redm[0][tid], m1 = redm[1][tid];
    float M = fmaxf(m0, m1);
    float S = reds[0][tid]*__expf(m0 - M) + reds[1][tid]*__expf(m1 - M);
    colPmax[(size_t)by*NROWS + bx*128 + tid] = M;
    colPsum[(size_t)by*NROWS + bx*128 + tid] = S;
  }
}

// ---------------- stage 2: merge 64 partials per row/col, sum LSE per block ----------------
__global__ __launch_bounds__(256) void lse_reduce(
    const float* __restrict__ rowPmax, const float* __restrict__ rowPsum,
    const float* __restrict__ colPmax, const float* __restrict__ colPsum,
    float* __restrict__ psums)
{
  const int i = blockIdx.x * 256 + threadIdx.x;
  const float* Pm = blockIdx.y ? colPmax : rowPmax;
  const float* Ps = blockIdx.y ? colPsum : rowPsum;
  float M = -__builtin_inff();
  float S = 0.f;
  for (int b = 0; b < 64; b++){
    float m = Pm[(size_t)b*NROWS + i];
    float s = Ps[(size_t)b*NROWS + i];
    float Mn = fmaxf(M, m);
    S = S * __expf(M - Mn) + s * __expf(m - Mn);
    M = Mn;
  }
  float lse = M + __logf(S);
  for (int o = 32; o; o >>= 1) lse += __shfl_down(lse, o);
  __shared__ float red[4];
  int lane = threadIdx.x & 63, wid = threadIdx.x >> 6;
  if (!lane) red[wid] = lse;
  __syncthreads();
  if (!threadIdx.x)
    psums[blockIdx.y*32 + blockIdx.x] = red[0]+red[1]+red[2]+red[3];
}

// ---------------- final: diagonal logits + combine ----------------
__global__ __launch_bounds__(256) void final_kernel(
    const float* __restrict__ psums, const float* __restrict__ vtime,
    const float* __restrict__ ttime, const float* __restrict__ diag,
    const float* __restrict__ cptr, float* __restrict__ out)
{
  int tid = threadIdx.x;
  float c = cptr[0];
  float slog = -(1.0f/sqrtf(c)) * TEMP_INV;
  float dsum = 0.f;
  for (int i = tid; i < NROWS; i += 256){
    float arg = c * (vtime[i]*ttime[i] - diag[i]);
    arg = fmaxf(arg, 1.0f + EPSX);
    dsum += slog * __logf(arg + sqrtf(arg*arg - 1.0f));
  }
  for (int o = 32; o; o >>= 1) dsum += __shfl_down(dsum, o);
  __shared__ float red[4];
  if (!(tid & 63)) red[tid >> 6] = dsum;
  __syncthreads();
  if (!tid){
    float dtot = red[0]+red[1]+red[2]+red[3];
    float rs = 0.f, cs = 0.f;
    for (int k = 0; k < 32; k++){ rs += psums[k]; cs += psums[32+k]; }
    out[0] = 0.5f*(rs + cs)/NROWS - dtot/NROWS;
  }
}

extern "C" void kernel_launch(void* const* d_in, const int* in_sizes, int n_in,
                              void* d_out, int out_size, void* d_ws, size_t ws_size,
                              hipStream_t stream) {
  const float* v = (const float*)d_in[0];
  const float* t = (const float*)d_in[1];
  const float* c = (const float*)d_in[2];

  char* ws = (char*)d_ws;
  const size_t NB = (size_t)NROWS * DDIM * sizeof(u16);   // 12,582,912
  u16*   vb      = (u16*)(ws);
  u16*   tb      = (u16*)(ws + NB);
  float* vtime   = (float*)(ws + 2*NB);
  float* ttime   = (float*)(ws + 2*NB + NROWS*4);
  float* diag    = (float*)(ws + 2*NB + 2*(size_t)NROWS*4);
  char*  p       = ws + 2*NB + 3*(size_t)NROWS*4;
  const size_t PB = (size_t)64 * NROWS * 4;               // 2 MB each
  float* rowPmax = (float*)(p);
  float* rowPsum = (float*)(p + PB);
  float* colPmax = (float*)(p + 2*PB);
  float* colPsum = (float*)(p + 3*PB);
  float* psums   = (float*)(p + 4*PB);

  prep_kernel<<<NROWS, 256, 0, stream>>>(v, t, c, vb, tb, vtime, ttime, diag);
  tile_kernel<<<dim3(64, 64), 256, 0, stream>>>(vb, tb, vtime, ttime, c,
                                                rowPmax, rowPsum, colPmax, colPsum);
  lse_reduce<<<dim3(32, 2), 256, 0, stream>>>(rowPmax, rowPsum, colPmax, colPsum, psums);
  final_kernel<<<1, 256, 0, stream>>>(psums, vtime, ttime, diag, c, (float*)d_out);
}

// Round 3
// 231.422 us; speedup vs baseline: 1.1824x; 1.1191x over previous
//
#include <hip/hip_runtime.h>
#include <hip/hip_bf16.h>
#include <math.h>

#define NROWS 8192
#define DDIM  768
#define TEMP_INV 14.285714285714286f   // 1/0.07
#define EPSX 1e-6f
#define NKT  24                        // 768 / 32

typedef __attribute__((ext_vector_type(8))) short bf16x8;
typedef __attribute__((ext_vector_type(4))) float f32x4;
typedef unsigned short u16;
typedef unsigned int   u32;

#define GLOAD16(gaddr, laddr)                                                   \
  __builtin_amdgcn_global_load_lds(                                             \
      (const __attribute__((address_space(1))) u32*)(gaddr),                    \
      (__attribute__((address_space(3))) u32*)(laddr), 16, 0, 0)

// round-to-nearest-even fp32 -> bf16 bits
__device__ __forceinline__ u16 f2bf(float x){
  u32 u = __float_as_uint(x);
  u = (u + 0x7fffu + ((u >> 16) & 1u)) >> 16;
  return (u16)u;
}

// ---------------- prep: bf16 convert + row norms + diagonal dot ----------------
__global__ __launch_bounds__(256) void prep_kernel(
    const float* __restrict__ v, const float* __restrict__ t, const float* __restrict__ cptr,
    u16* __restrict__ vb, u16* __restrict__ tb,
    float* __restrict__ vtime, float* __restrict__ ttime, float* __restrict__ diag)
{
  int row = blockIdx.x;
  int tid = threadIdx.x;
  float inv_c = 1.0f / cptr[0];
  const float* vr = v + (size_t)row * DDIM;
  const float* tr = t + (size_t)row * DDIM;
  u16* vbr = vb + (size_t)row * DDIM;
  u16* tbr = tb + (size_t)row * DDIM;
  float sv = 0.f, st = 0.f, dd = 0.f;
  for (int k = tid; k < DDIM; k += 256){
    float a = vr[k], b = tr[k];
    sv += a*a; st += b*b; dd += a*b;
    vbr[k] = f2bf(a);
    tbr[k] = f2bf(b);
  }
  for (int o = 32; o; o >>= 1){
    sv += __shfl_down(sv, o);
    st += __shfl_down(st, o);
    dd += __shfl_down(dd, o);
  }
  __shared__ float red[3][4];
  int lane = tid & 63, wid = tid >> 6;
  if (!lane){ red[0][wid]=sv; red[1][wid]=st; red[2][wid]=dd; }
  __syncthreads();
  if (!tid){
    float SV = red[0][0]+red[0][1]+red[0][2]+red[0][3];
    float ST = red[1][0]+red[1][1]+red[1][2]+red[1][3];
    float DD = red[2][0]+red[2][1]+red[2][2]+red[2][3];
    vtime[row] = sqrtf(inv_c + SV);
    ttime[row] = sqrtf(inv_c + DD*0.f + ST);   // keep simple
    diag[row]  = DD;
  }
}

// ---------------- main: 256x256 tile, 8 waves, 4-deep LDS pipeline, counted vmcnt ----
// LDS: 4 K-tile buffers x (A 16KB + B 16KB) = 128KB. Buffer b at u16 offset b*16384,
// A region [0,8192), B region [8192,16384). Row = 32 u16 (64B). Swizzle: 16B-slot
// index (bits[5:4] of byte offset) XOR'd with (row>>1)&3 (bits[8:7]); the inverse
// swizzle is applied on the global source of global_load_lds (linear LDS dest).
__global__ __launch_bounds__(512, 2) void tile_kernel(
    const u16* __restrict__ vb, const u16* __restrict__ tb,
    const float* __restrict__ vtime, const float* __restrict__ ttime,
    const float* __restrict__ cptr,
    float* __restrict__ rowPmax, float* __restrict__ rowPsum,
    float* __restrict__ colPmax, float* __restrict__ colPsum)
{
  __shared__ u16 SM[65536];            // 128 KB staging, reused for reductions
  __shared__ float vtl[256], ttl[256];

  const int tid = threadIdx.x;
  const int lane = tid & 63, wid = tid >> 6;
  const int wm = wid >> 2, wn = wid & 3;      // 2 x 4 wave grid; wave owns 128x64
  const int lo = lane & 15, hi = lane >> 4;

  // XCD-aware bijective swizzle (nwg=1024, 1024%8==0)
  const int linear = blockIdx.y * 32 + blockIdx.x;
  const int swz = (linear & 7) * 128 + (linear >> 3);
  const int bx = swz & 31, by = swz >> 5;

  if (tid < 256){ vtl[tid] = vtime[by*256 + tid]; ttl[tid] = ttime[bx*256 + tid]; }

  const float c = cptr[0];
  const float slog = -(1.0f/sqrtf(c)) * TEMP_INV;

  const u16* Abase = vb + (size_t)(by*256) * DDIM;
  const u16* Bbase = tb + (size_t)(bx*256) * DDIM;

  // staging: 2 gload insts per matrix per K-tile per wave; inst covers 16 rows (1KB)
  int g_off[2], l_base[2];
  #pragma unroll
  for (int a = 0; a < 2; a++){
    int lb = (wid*2 + a) * 512;        // u16 base within region (wave-uniform)
    int lu = lb + lane*8;              // this lane's linear u16 position
    int r  = lu >> 5;                  // row (32 u16 per row)
    int slot = ((lu >> 3) & 3) ^ ((r >> 1) & 3);   // inverse swizzle on source
    g_off[a] = r*DDIM + slot*8;        // u16 element offset (add t*32 per tile)
    l_base[a] = lb;
  }

  // fragment ds_read offsets (u16), swizzled
  int aoff[8], boff[4];
  #pragma unroll
  for (int m = 0; m < 8; m++){
    int r = wm*128 + m*16 + lo;
    aoff[m] = r*32 + ((hi ^ ((r>>1)&3)) << 3);
  }
  #pragma unroll
  for (int n = 0; n < 4; n++){
    int cN = wn*64 + n*16 + lo;
    boff[n] = 8192 + cN*32 + ((hi ^ ((cN>>1)&3)) << 3);
  }

#define STAGE_A(t) { u16* d_ = SM + (((t)&3)<<14);                               \
    GLOAD16(Abase + g_off[0] + (t)*32, d_ + l_base[0]);                          \
    GLOAD16(Abase + g_off[1] + (t)*32, d_ + l_base[1]); }
#define STAGE_B(t) { u16* d_ = SM + (((t)&3)<<14) + 8192;                        \
    GLOAD16(Bbase + g_off[0] + (t)*32, d_ + l_base[0]);                          \
    GLOAD16(Bbase + g_off[1] + (t)*32, d_ + l_base[1]); }

  f32x4 acc[8][4];
  #pragma unroll
  for (int m = 0; m < 8; m++)
    #pragma unroll
    for (int n = 0; n < 4; n++)
      acc[m][n] = (f32x4){0.f,0.f,0.f,0.f};

  // prologue: prefetch K-tiles 0,1,2 (12 loads in flight)
  STAGE_A(0); STAGE_B(0);
  STAGE_A(1); STAGE_B(1);
  STAGE_A(2); STAGE_B(2);

  for (int t = 0; t < NKT; t++){
    const u16* Ab = SM + ((t & 3) << 14);
    // retire exactly tile t's 4 loads; keep later prefetches in flight
    if (t < NKT-2)       asm volatile("s_waitcnt vmcnt(8)\n\ts_barrier" ::: "memory");
    else if (t == NKT-2) asm volatile("s_waitcnt vmcnt(4)\n\ts_barrier" ::: "memory");
    else                 asm volatile("s_waitcnt vmcnt(0)\n\ts_barrier" ::: "memory");

    bf16x8 bfr[4], af[4];
    // phase 1: B frags + A frags m0..3, issue A prefetch, MFMA quadrant 0
    #pragma unroll
    for (int n = 0; n < 4; n++) bfr[n] = *(const bf16x8*)(Ab + boff[n]);
    #pragma unroll
    for (int m = 0; m < 4; m++) af[m]  = *(const bf16x8*)(Ab + aoff[m]);
    if (t < NKT-3) STAGE_A(t+3);
    __builtin_amdgcn_s_setprio(1);
    #pragma unroll
    for (int m = 0; m < 4; m++)
      #pragma unroll
      for (int n = 0; n < 4; n++)
        acc[m][n] = __builtin_amdgcn_mfma_f32_16x16x32_bf16(af[m], bfr[n], acc[m][n], 0, 0, 0);
    __builtin_amdgcn_s_setprio(0);
    // phase 2: A frags m4..7, issue B prefetch, MFMA quadrant 1
    #pragma unroll
    for (int m = 0; m < 4; m++) af[m] = *(const bf16x8*)(Ab + aoff[4+m]);
    if (t < NKT-3) STAGE_B(t+3);
    __builtin_amdgcn_s_setprio(1);
    #pragma unroll
    for (int m = 0; m < 4; m++)
      #pragma unroll
      for (int n = 0; n < 4; n++)
        acc[4+m][n] = __builtin_amdgcn_mfma_f32_16x16x32_bf16(af[m], bfr[n], acc[4+m][n], 0, 0, 0);
    __builtin_amdgcn_s_setprio(0);
  }

  __syncthreads();   // drain everything; staging LDS now reusable for reductions

  // ---- logit transform in-place ----
  // C/D layout: col = lane&15, row = (lane>>4)*4 + j
  #pragma unroll
  for (int m = 0; m < 8; m++){
    #pragma unroll
    for (int n = 0; n < 4; n++){
      #pragma unroll
      for (int j = 0; j < 4; j++){
        int r  = wm*128 + m*16 + hi*4 + j;
        int cc = wn*64  + n*16 + lo;
        float arg = c * (vtl[r] * ttl[cc] - acc[m][n][j]);
        arg = fmaxf(arg, 1.0f + EPSX);
        acc[m][n][j] = slog * __logf(arg + sqrtf(arg*arg - 1.0f));
      }
    }
  }

  float* redm  = (float*)SM;           // [4][256]
  float* reds  = redm + 1024;          // [4][256]
  float* redcm = reds + 1024;          // [2][256]
  float* redcs = redcm + 512;          // [2][256]

  // ---- per-row (max, sumexp) over the tile's 256 cols ----
  #pragma unroll
  for (int m = 0; m < 8; m++){
    #pragma unroll
    for (int j = 0; j < 4; j++){
      float mx = fmaxf(fmaxf(acc[m][0][j], acc[m][1][j]), fmaxf(acc[m][2][j], acc[m][3][j]));
      #pragma unroll
      for (int msk = 1; msk < 16; msk <<= 1) mx = fmaxf(mx, __shfl_xor(mx, msk));
      float s = 0.f;
      #pragma unroll
      for (int n = 0; n < 4; n++) s += __expf(acc[m][n][j] - mx);
      #pragma unroll
      for (int msk = 1; msk < 16; msk <<= 1) s += __shfl_xor(s, msk);
      if (lo == 0){
        int rt = wm*128 + m*16 + hi*4 + j;
        redm[wn*256 + rt] = mx;
        reds[wn*256 + rt] = s;
      }
    }
  }
  __syncthreads();
  if (tid < 256){
    float M = redm[tid];
    M = fmaxf(M, redm[256 + tid]);
    M = fmaxf(M, redm[512 + tid]);
    M = fmaxf(M, redm[768 + tid]);
    float S = reds[tid]      * __expf(redm[tid]       - M)
            + reds[256+tid]  * __expf(redm[256 + tid] - M)
            + reds[512+tid]  * __expf(redm[512 + tid] - M)
            + reds[768+tid]  * __expf(redm[768 + tid] - M);
    rowPmax[(size_t)bx*NROWS + by*256 + tid] = M;
    rowPsum[(size_t)bx*NROWS + by*256 + tid] = S;
  }

  // ---- per-col (max, sumexp) over the tile's 256 rows ----
  #pragma unroll
  for (int n = 0; n < 4; n++){
    float mx = -__builtin_inff();
    #pragma unroll
    for (int m = 0; m < 8; m++)
      #pragma unroll
      for (int j = 0; j < 4; j++) mx = fmaxf(mx, acc[m][n][j]);
    mx = fmaxf(mx, __shfl_xor(mx, 16));
    mx = fmaxf(mx, __shfl_xor(mx, 32));
    float s = 0.f;
    #pragma unroll
    for (int m = 0; m < 8; m++)
      #pragma unroll
      for (int j = 0; j < 4; j++) s += __expf(acc[m][n][j] - mx);
    s += __shfl_xor(s, 16);
    s += __shfl_xor(s, 32);
    if (hi == 0){
      int ct = wn*64 + n*16 + lo;
      redcm[wm*256 + ct] = mx;
      redcs[wm*256 + ct] = s;
    }
  }
  __syncthreads();
  if (tid < 256){
    float m0 = redcm[tid], m1 = redcm[256 + tid];
    float M = fmaxf(m0, m1);
    float S = redcs[tid]*__expf(m0 - M) + redcs[256 + tid]*__expf(m1 - M);
    colPmax[(size_t)by*NROWS + bx*256 + tid] = M;
    colPsum[(size_t)by*NROWS + bx*256 + tid] = S;
  }
#undef STAGE_A
#undef STAGE_B
}

// ---------------- stage 2: merge 32 partials per row/col, sum LSE per block ----------------
__global__ __launch_bounds__(256) void lse_reduce(
    const float* __restrict__ rowPmax, const float* __restrict__ rowPsum,
    const float* __restrict__ colPmax, const float* __restrict__ colPsum,
    float* __restrict__ psums)
{
  const int i = blockIdx.x * 256 + threadIdx.x;
  const float* Pm = blockIdx.y ? colPmax : rowPmax;
  const float* Ps = blockIdx.y ? colPsum : rowPsum;
  float M = -__builtin_inff();
  float S = 0.f;
  for (int b = 0; b < 32; b++){
    float m = Pm[(size_t)b*NROWS + i];
    float s = Ps[(size_t)b*NROWS + i];
    float Mn = fmaxf(M, m);
    S = S * __expf(M - Mn) + s * __expf(m - Mn);
    M = Mn;
  }
  float lse = M + __logf(S);
  for (int o = 32; o; o >>= 1) lse += __shfl_down(lse, o);
  __shared__ float red[4];
  int lane = threadIdx.x & 63, wid = threadIdx.x >> 6;
  if (!lane) red[wid] = lse;
  __syncthreads();
  if (!threadIdx.x)
    psums[blockIdx.y*32 + blockIdx.x] = red[0]+red[1]+red[2]+red[3];
}

// ---------------- final: diagonal logits + combine ----------------
__global__ __launch_bounds__(256) void final_kernel(
    const float* __restrict__ psums, const float* __restrict__ vtime,
    const float* __restrict__ ttime, const float* __restrict__ diag,
    const float* __restrict__ cptr, float* __restrict__ out)
{
  int tid = threadIdx.x;
  float c = cptr[0];
  float slog = -(1.0f/sqrtf(c)) * TEMP_INV;
  float dsum = 0.f;
  for (int i = tid; i < NROWS; i += 256){
    float arg = c * (vtime[i]*ttime[i] - diag[i]);
    arg = fmaxf(arg, 1.0f + EPSX);
    dsum += slog * __logf(arg + sqrtf(arg*arg - 1.0f));
  }
  for (int o = 32; o; o >>= 1) dsum += __shfl_down(dsum, o);
  __shared__ float red[4];
  if (!(tid & 63)) red[tid >> 6] = dsum;
  __syncthreads();
  if (!tid){
    float dtot = red[0]+red[1]+red[2]+red[3];
    float rs = 0.f, cs = 0.f;
    for (int k = 0; k < 32; k++){ rs += psums[k]; cs += psums[32+k]; }
    out[0] = 0.5f*(rs + cs)/NROWS - dtot/NROWS;
  }
}

extern "C" void kernel_launch(void* const* d_in, const int* in_sizes, int n_in,
                              void* d_out, int out_size, void* d_ws, size_t ws_size,
                              hipStream_t stream) {
  const float* v = (const float*)d_in[0];
  const float* t = (const float*)d_in[1];
  const float* c = (const float*)d_in[2];

  char* ws = (char*)d_ws;
  const size_t NB = (size_t)NROWS * DDIM * sizeof(u16);   // 12,582,912
  u16*   vb      = (u16*)(ws);
  u16*   tb      = (u16*)(ws + NB);
  float* vtime   = (float*)(ws + 2*NB);
  float* ttime   = (float*)(ws + 2*NB + NROWS*4);
  float* diag    = (float*)(ws + 2*NB + 2*(size_t)NROWS*4);
  char*  p       = ws + 2*NB + 3*(size_t)NROWS*4;
  const size_t PB = (size_t)32 * NROWS * 4;               // 1 MB each
  float* rowPmax = (float*)(p);
  float* rowPsum = (float*)(p + PB);
  float* colPmax = (float*)(p + 2*PB);
  float* colPsum = (float*)(p + 3*PB);
  float* psums   = (float*)(p + 4*PB);

  prep_kernel<<<NROWS, 256, 0, stream>>>(v, t, c, vb, tb, vtime, ttime, diag);
  tile_kernel<<<dim3(32, 32), 512, 0, stream>>>(vb, tb, vtime, ttime, c,
                                                rowPmax, rowPsum, colPmax, colPsum);
  lse_reduce<<<dim3(32, 2), 256, 0, stream>>>(rowPmax, rowPsum, colPmax, colPsum, psums);
  final_kernel<<<1, 256, 0, stream>>>(psums, vtime, ttime, diag, c, (float*)d_out);
}

// Round 4
// 228.769 us; speedup vs baseline: 1.1961x; 1.0116x over previous
//
#include <hip/hip_runtime.h>
#include <hip/hip_bf16.h>
#include <math.h>

#define NROWS 8192
#define DDIM  768
#define TEMP_INV 14.285714285714286f   // 1/0.07
#define EPSX 1e-6f
#define NKT  12                        // 768 / 64 K-tiles

typedef __attribute__((ext_vector_type(8))) short bf16x8;
typedef __attribute__((ext_vector_type(4))) float f32x4;
typedef unsigned short u16;
typedef unsigned int   u32;

#define GLOAD16(gaddr, laddr)                                                   \
  __builtin_amdgcn_global_load_lds(                                             \
      (const __attribute__((address_space(1))) u32*)(gaddr),                    \
      (__attribute__((address_space(3))) u32*)(laddr), 16, 0, 0)

#define MFMA16(a,b,c) __builtin_amdgcn_mfma_f32_16x16x32_bf16((a),(b),(c),0,0,0)

// round-to-nearest-even fp32 -> bf16 bits
__device__ __forceinline__ u16 f2bf(float x){
  u32 u = __float_as_uint(x);
  u = (u + 0x7fffu + ((u >> 16) & 1u)) >> 16;
  return (u16)u;
}

// ---------------- prep: bf16 convert + row norms + diagonal dot ----------------
__global__ __launch_bounds__(256) void prep_kernel(
    const float* __restrict__ v, const float* __restrict__ t, const float* __restrict__ cptr,
    u16* __restrict__ vb, u16* __restrict__ tb,
    float* __restrict__ vtime, float* __restrict__ ttime, float* __restrict__ diag)
{
  int row = blockIdx.x;
  int tid = threadIdx.x;
  float inv_c = 1.0f / cptr[0];
  const float* vr = v + (size_t)row * DDIM;
  const float* tr = t + (size_t)row * DDIM;
  u16* vbr = vb + (size_t)row * DDIM;
  u16* tbr = tb + (size_t)row * DDIM;
  float sv = 0.f, st = 0.f, dd = 0.f;
  for (int k = tid; k < DDIM; k += 256){
    float a = vr[k], b = tr[k];
    sv += a*a; st += b*b; dd += a*b;
    vbr[k] = f2bf(a);
    tbr[k] = f2bf(b);
  }
  for (int o = 32; o; o >>= 1){
    sv += __shfl_down(sv, o);
    st += __shfl_down(st, o);
    dd += __shfl_down(dd, o);
  }
  __shared__ float red[3][4];
  int lane = tid & 63, wid = tid >> 6;
  if (!lane){ red[0][wid]=sv; red[1][wid]=st; red[2][wid]=dd; }
  __syncthreads();
  if (!tid){
    float SV = red[0][0]+red[0][1]+red[0][2]+red[0][3];
    float ST = red[1][0]+red[1][1]+red[1][2]+red[1][3];
    float DD = red[2][0]+red[2][1]+red[2][2]+red[2][3];
    vtime[row] = sqrtf(inv_c + SV);
    ttime[row] = sqrtf(inv_c + ST);
    diag[row]  = DD;
  }
}

// ---------------- main: 256x256 tile, BK=64, 8-phase m201-style schedule --------
// LDS: 2 slots x (A 256x64 + B 256x64) bf16 = 128KB. Slot s at u16 offset s*32768;
// A at +0 (16384 u16), B at +16384. Row = 64 u16 (128B). Swizzle: 16B-slot index
// (3 bits) XOR'd with row&7 on BOTH the global source of global_load_lds (linear
// LDS dest) and the ds_read address (rule #21 involution).
// Stage units per K-tile tau (2 gloads each): B01 @ (tau-2).q3, B23 @ (tau-1).q0,
// A01 @ (tau-1).q1, A23 @ (tau-1).q2.  vmcnt(2) once per K-tile at q3.
__global__ __launch_bounds__(512, 2) void tile_kernel(
    const u16* __restrict__ vb, const u16* __restrict__ tb,
    const float* __restrict__ vtime, const float* __restrict__ ttime,
    const float* __restrict__ cptr,
    float* __restrict__ rowPmax, float* __restrict__ rowPsum,
    float* __restrict__ colPmax, float* __restrict__ colPsum)
{
  __shared__ u16 SM[65536];            // 128 KB staging, reused for reductions
  __shared__ float vtl[256], ttl[256];

  const int tid = threadIdx.x;
  const int lane = tid & 63, wid = tid >> 6;
  const int wm = wid >> 2, wn = wid & 3;      // 2 x 4 wave grid; wave owns 128x64
  const int lo = lane & 15, hi = lane >> 4;

  // XCD-aware bijective swizzle (nwg=1024, 1024%8==0)
  const int linear = blockIdx.y * 32 + blockIdx.x;
  const int swz = (linear & 7) * 128 + (linear >> 3);
  const int bx = swz & 31, by = swz >> 5;

  if (tid < 256){ vtl[tid] = vtime[by*256 + tid]; ttl[tid] = ttime[bx*256 + tid]; }

  const float c = cptr[0];
  const float slog = -(1.0f/sqrtf(c)) * TEMP_INV;

  const u16* Abase = vb + (size_t)(by*256) * DDIM;
  const u16* Bbase = tb + (size_t)(bx*256) * DDIM;

  // stage source offsets (per-lane, inverse-swizzled), a = 0..3 (8 rows each)
  int goff[4];
  #pragma unroll
  for (int a = 0; a < 4; a++){
    int r = wid*32 + a*8 + (lane >> 3);
    goff[a] = r*DDIM + (((lane & 7) ^ (r & 7)) * 8);
  }

  // ds_read swizzle terms (row&7 == lo&7 since row bases are multiples of 8)
  const int sw0 = ((hi     ^ (lo & 7)) * 8);
  const int sw1 = (((4+hi) ^ (lo & 7)) * 8);
  const int arow = (wm*128 + lo) * 64;
  const int brow = (wn*64  + lo) * 64 + 16384;

  f32x4 acc[8][4];
  #pragma unroll
  for (int m = 0; m < 8; m++)
    #pragma unroll
    for (int n = 0; n < 4; n++)
      acc[m][n] = (f32x4){0.f,0.f,0.f,0.f};

  // stage one gload-pair (one unit): matB in {0,1}, ap in {0,1} (rows ap*16..+16)
#define ST2(matB, ap, kt) do{ if ((kt) < NKT){                                   \
    u16* d_ = SM + (((kt)&1)<<15) + ((matB)?16384:0) + wid*2048 + (ap)*1024;     \
    const u16* g_ = ((matB)? Bbase : Abase) + (kt)*64;                           \
    GLOAD16(g_ + goff[(ap)*2],   d_);                                            \
    GLOAD16(g_ + goff[(ap)*2+1], d_ + 512); } }while(0)

  // prologue: B01(0) B23(0) A01(0) A23(0) B01(1) -> 10 loads; keep B01(1) in flight
  ST2(1,0,0); ST2(1,1,0); ST2(0,0,0); ST2(0,1,0); ST2(1,0,1);
  asm volatile("s_waitcnt vmcnt(2)" ::: "memory");
  __builtin_amdgcn_s_barrier();

  for (int t = 0; t < NKT; t++){
    const u16* S = SM + ((t & 1) << 15);
    bf16x8 b0[4], b1[4], a00, a01, a10, a11;

    // ======== phase 0: read all B (8) + A m0,m1 (4); stage B23(t+1) ========
    #pragma unroll
    for (int n = 0; n < 4; n++){
      b0[n] = *(const bf16x8*)(S + brow + n*1024 + sw0);
      b1[n] = *(const bf16x8*)(S + brow + n*1024 + sw1);
    }
    a00 = *(const bf16x8*)(S + arow           + sw0);
    a01 = *(const bf16x8*)(S + arow           + sw1);
    a10 = *(const bf16x8*)(S + arow + 1*1024  + sw0);
    a11 = *(const bf16x8*)(S + arow + 1*1024  + sw1);
    ST2(1,1,t+1);
    asm volatile("s_waitcnt lgkmcnt(8)" ::: "memory");
    __builtin_amdgcn_s_barrier();
    asm volatile("s_waitcnt lgkmcnt(0)" ::: "memory");
    __builtin_amdgcn_sched_barrier(0);
    __builtin_amdgcn_s_setprio(1);
    #pragma unroll
    for (int n = 0; n < 4; n++){
      acc[0][n] = MFMA16(a00, b0[n], acc[0][n]);
      acc[0][n] = MFMA16(a01, b1[n], acc[0][n]);
      acc[1][n] = MFMA16(a10, b0[n], acc[1][n]);
      acc[1][n] = MFMA16(a11, b1[n], acc[1][n]);
    }
    __builtin_amdgcn_s_setprio(0);
    __builtin_amdgcn_s_barrier();

    // ======== phase 1: A m2,m3; stage A01(t+1) ========
    a00 = *(const bf16x8*)(S + arow + 2*1024 + sw0);
    a01 = *(const bf16x8*)(S + arow + 2*1024 + sw1);
    a10 = *(const bf16x8*)(S + arow + 3*1024 + sw0);
    a11 = *(const bf16x8*)(S + arow + 3*1024 + sw1);
    ST2(0,0,t+1);
    __builtin_amdgcn_s_barrier();
    asm volatile("s_waitcnt lgkmcnt(0)" ::: "memory");
    __builtin_amdgcn_sched_barrier(0);
    __builtin_amdgcn_s_setprio(1);
    #pragma unroll
    for (int n = 0; n < 4; n++){
      acc[2][n] = MFMA16(a00, b0[n], acc[2][n]);
      acc[2][n] = MFMA16(a01, b1[n], acc[2][n]);
      acc[3][n] = MFMA16(a10, b0[n], acc[3][n]);
      acc[3][n] = MFMA16(a11, b1[n], acc[3][n]);
    }
    __builtin_amdgcn_s_setprio(0);
    __builtin_amdgcn_s_barrier();

    // ======== phase 2: A m4,m5; stage A23(t+1) ========
    a00 = *(const bf16x8*)(S + arow + 4*1024 + sw0);
    a01 = *(const bf16x8*)(S + arow + 4*1024 + sw1);
    a10 = *(const bf16x8*)(S + arow + 5*1024 + sw0);
    a11 = *(const bf16x8*)(S + arow + 5*1024 + sw1);
    ST2(0,1,t+1);
    __builtin_amdgcn_s_barrier();
    asm volatile("s_waitcnt lgkmcnt(0)" ::: "memory");
    __builtin_amdgcn_sched_barrier(0);
    __builtin_amdgcn_s_setprio(1);
    #pragma unroll
    for (int n = 0; n < 4; n++){
      acc[4][n] = MFMA16(a00, b0[n], acc[4][n]);
      acc[4][n] = MFMA16(a01, b1[n], acc[4][n]);
      acc[5][n] = MFMA16(a10, b0[n], acc[5][n]);
      acc[5][n] = MFMA16(a11, b1[n], acc[5][n]);
    }
    __builtin_amdgcn_s_setprio(0);
    __builtin_amdgcn_s_barrier();

    // ======== phase 3: A m6,m7; stage B01(t+2); vmcnt ========
    a00 = *(const bf16x8*)(S + arow + 6*1024 + sw0);
    a01 = *(const bf16x8*)(S + arow + 6*1024 + sw1);
    a10 = *(const bf16x8*)(S + arow + 7*1024 + sw0);
    a11 = *(const bf16x8*)(S + arow + 7*1024 + sw1);
    ST2(1,0,t+2);
    if (t <= 9) asm volatile("s_waitcnt vmcnt(2)" ::: "memory");
    else        asm volatile("s_waitcnt vmcnt(0)" ::: "memory");
    __builtin_amdgcn_s_barrier();
    asm volatile("s_waitcnt lgkmcnt(0)" ::: "memory");
    __builtin_amdgcn_sched_barrier(0);
    __builtin_amdgcn_s_setprio(1);
    #pragma unroll
    for (int n = 0; n < 4; n++){
      acc[6][n] = MFMA16(a00, b0[n], acc[6][n]);
      acc[6][n] = MFMA16(a01, b1[n], acc[6][n]);
      acc[7][n] = MFMA16(a10, b0[n], acc[7][n]);
      acc[7][n] = MFMA16(a11, b1[n], acc[7][n]);
    }
    __builtin_amdgcn_s_setprio(0);
    __builtin_amdgcn_s_barrier();
  }
#undef ST2

  __syncthreads();   // drain; staging LDS now reusable for reductions

  // ---- logit transform in-place ----
  // C/D layout: col = lane&15, row = (lane>>4)*4 + j
  #pragma unroll
  for (int m = 0; m < 8; m++){
    #pragma unroll
    for (int n = 0; n < 4; n++){
      #pragma unroll
      for (int j = 0; j < 4; j++){
        int r  = wm*128 + m*16 + hi*4 + j;
        int cc = wn*64  + n*16 + lo;
        float arg = c * (vtl[r] * ttl[cc] - acc[m][n][j]);
        arg = fmaxf(arg, 1.0f + EPSX);
        acc[m][n][j] = slog * __logf(arg + sqrtf(arg*arg - 1.0f));
      }
    }
  }

  float* redm  = (float*)SM;           // [4][256]
  float* reds  = redm + 1024;          // [4][256]
  float* redcm = reds + 1024;          // [2][256]
  float* redcs = redcm + 512;          // [2][256]

  // ---- per-row (max, sumexp) over the tile's 256 cols ----
  #pragma unroll
  for (int m = 0; m < 8; m++){
    #pragma unroll
    for (int j = 0; j < 4; j++){
      float mx = fmaxf(fmaxf(acc[m][0][j], acc[m][1][j]), fmaxf(acc[m][2][j], acc[m][3][j]));
      #pragma unroll
      for (int msk = 1; msk < 16; msk <<= 1) mx = fmaxf(mx, __shfl_xor(mx, msk));
      float s = 0.f;
      #pragma unroll
      for (int n = 0; n < 4; n++) s += __expf(acc[m][n][j] - mx);
      #pragma unroll
      for (int msk = 1; msk < 16; msk <<= 1) s += __shfl_xor(s, msk);
      if (lo == 0){
        int rt = wm*128 + m*16 + hi*4 + j;
        redm[wn*256 + rt] = mx;
        reds[wn*256 + rt] = s;
      }
    }
  }
  __syncthreads();
  if (tid < 256){
    float M = redm[tid];
    M = fmaxf(M, redm[256 + tid]);
    M = fmaxf(M, redm[512 + tid]);
    M = fmaxf(M, redm[768 + tid]);
    float S = reds[tid]      * __expf(redm[tid]       - M)
            + reds[256+tid]  * __expf(redm[256 + tid] - M)
            + reds[512+tid]  * __expf(redm[512 + tid] - M)
            + reds[768+tid]  * __expf(redm[768 + tid] - M);
    rowPmax[(size_t)bx*NROWS + by*256 + tid] = M;
    rowPsum[(size_t)bx*NROWS + by*256 + tid] = S;
  }

  // ---- per-col (max, sumexp) over the tile's 256 rows ----
  #pragma unroll
  for (int n = 0; n < 4; n++){
    float mx = -__builtin_inff();
    #pragma unroll
    for (int m = 0; m < 8; m++)
      #pragma unroll
      for (int j = 0; j < 4; j++) mx = fmaxf(mx, acc[m][n][j]);
    mx = fmaxf(mx, __shfl_xor(mx, 16));
    mx = fmaxf(mx, __shfl_xor(mx, 32));
    float s = 0.f;
    #pragma unroll
    for (int m = 0; m < 8; m++)
      #pragma unroll
      for (int j = 0; j < 4; j++) s += __expf(acc[m][n][j] - mx);
    s += __shfl_xor(s, 16);
    s += __shfl_xor(s, 32);
    if (hi == 0){
      int ct = wn*64 + n*16 + lo;
      redcm[wm*256 + ct] = mx;
      redcs[wm*256 + ct] = s;
    }
  }
  __syncthreads();
  if (tid < 256){
    float m0 = redcm[tid], m1 = redcm[256 + tid];
    float M = fmaxf(m0, m1);
    float S = redcs[tid]*__expf(m0 - M) + redcs[256 + tid]*__expf(m1 - M);
    colPmax[(size_t)by*NROWS + bx*256 + tid] = M;
    colPsum[(size_t)by*NROWS + bx*256 + tid] = S;
  }
}

// ---------------- stage 2: merge 32 partials per row/col, sum LSE per block ----------------
__global__ __launch_bounds__(256) void lse_reduce(
    const float* __restrict__ rowPmax, const float* __restrict__ rowPsum,
    const float* __restrict__ colPmax, const float* __restrict__ colPsum,
    float* __restrict__ psums)
{
  const int i = blockIdx.x * 256 + threadIdx.x;
  const float* Pm = blockIdx.y ? colPmax : rowPmax;
  const float* Ps = blockIdx.y ? colPsum : rowPsum;
  float M = -__builtin_inff();
  float S = 0.f;
  for (int b = 0; b < 32; b++){
    float m = Pm[(size_t)b*NROWS + i];
    float s = Ps[(size_t)b*NROWS + i];
    float Mn = fmaxf(M, m);
    S = S * __expf(M - Mn) + s * __expf(m - Mn);
    M = Mn;
  }
  float lse = M + __logf(S);
  for (int o = 32; o; o >>= 1) lse += __shfl_down(lse, o);
  __shared__ float red[4];
  int lane = threadIdx.x & 63, wid = threadIdx.x >> 6;
  if (!lane) red[wid] = lse;
  __syncthreads();
  if (!threadIdx.x)
    psums[blockIdx.y*32 + blockIdx.x] = red[0]+red[1]+red[2]+red[3];
}

// ---------------- final: diagonal logits + combine ----------------
__global__ __launch_bounds__(256) void final_kernel(
    const float* __restrict__ psums, const float* __restrict__ vtime,
    const float* __restrict__ ttime, const float* __restrict__ diag,
    const float* __restrict__ cptr, float* __restrict__ out)
{
  int tid = threadIdx.x;
  float c = cptr[0];
  float slog = -(1.0f/sqrtf(c)) * TEMP_INV;
  float dsum = 0.f;
  for (int i = tid; i < NROWS; i += 256){
    float arg = c * (vtime[i]*ttime[i] - diag[i]);
    arg = fmaxf(arg, 1.0f + EPSX);
    dsum += slog * __logf(arg + sqrtf(arg*arg - 1.0f));
  }
  for (int o = 32; o; o >>= 1) dsum += __shfl_down(dsum, o);
  __shared__ float red[4];
  if (!(tid & 63)) red[tid >> 6] = dsum;
  __syncthreads();
  if (!tid){
    float dtot = red[0]+red[1]+red[2]+red[3];
    float rs = 0.f, cs = 0.f;
    for (int k = 0; k < 32; k++){ rs += psums[k]; cs += psums[32+k]; }
    out[0] = 0.5f*(rs + cs)/NROWS - dtot/NROWS;
  }
}

extern "C" void kernel_launch(void* const* d_in, const int* in_sizes, int n_in,
                              void* d_out, int out_size, void* d_ws, size_t ws_size,
                              hipStream_t stream) {
  const float* v = (const float*)d_in[0];
  const float* t = (const float*)d_in[1];
  const float* c = (const float*)d_in[2];

  char* ws = (char*)d_ws;
  const size_t NB = (size_t)NROWS * DDIM * sizeof(u16);   // 12,582,912
  u16*   vb      = (u16*)(ws);
  u16*   tb      = (u16*)(ws + NB);
  float* vtime   = (float*)(ws + 2*NB);
  float* ttime   = (float*)(ws + 2*NB + NROWS*4);
  float* diag    = (float*)(ws + 2*NB + 2*(size_t)NROWS*4);
  char*  p       = ws + 2*NB + 3*(size_t)NROWS*4;
  const size_t PB = (size_t)32 * NROWS * 4;               // 1 MB each
  float* rowPmax = (float*)(p);
  float* rowPsum = (float*)(p + PB);
  float* colPmax = (float*)(p + 2*PB);
  float* colPsum = (float*)(p + 3*PB);
  float* psums   = (float*)(p + 4*PB);

  prep_kernel<<<NROWS, 256, 0, stream>>>(v, t, c, vb, tb, vtime, ttime, diag);
  tile_kernel<<<dim3(32, 32), 512, 0, stream>>>(vb, tb, vtime, ttime, c,
                                                rowPmax, rowPsum, colPmax, colPsum);
  lse_reduce<<<dim3(32, 2), 256, 0, stream>>>(rowPmax, rowPsum, colPmax, colPsum, psums);
  final_kernel<<<1, 256, 0, stream>>>(psums, vtime, ttime, diag, c, (float*)d_out);
}